// Round 2
// baseline (166.639 us; speedup 1.0000x reference)
//
#include <hip/hip_runtime.h>
#include <cstdint>
#include <cstddef>

// ---------------------------------------------------------------------------
// MultiHeadExternalAttention, algebraically collapsed:
//   logits = x @ Wk   (Wk[e,hm] = sum_d W_in[e,h*128+d]*W_mk[d,m]) + bk
//   attn   = softmax_n(logits); attn /= (sum_m attn + 1e-9)
//   out    = attn @ Wv (Wv[hm,e] = sum_d W_mv[m,d]*W_out[h*128+d,e]) + bv
// B=32 N=1024 E=512 H=16 M=16 HM=256 ROWS=32768
// Inputs fp32 (reference dtypes), output fp32. Internals bf16 via MFMA.
// ---------------------------------------------------------------------------

typedef unsigned short u16;
typedef unsigned int u32;
typedef short s16x8 __attribute__((ext_vector_type(8)));
typedef float f32x4 __attribute__((ext_vector_type(4)));

#define ROWS 32768
#define HM   256
#define EDIM 512

// workspace layout (bytes)
constexpr size_t OFF_FLAG = 0;
constexpr size_t OFF_WKT  = 1u << 20;                 // u16 [256][512]  (256 KiB)
constexpr size_t OFF_WVT  = OFF_WKT + (1u << 18);     // u16 [512][256]  (256 KiB)
constexpr size_t OFF_BK   = OFF_WVT + (1u << 18);     // f32 [256]
constexpr size_t OFF_BV   = OFF_BK + 4096;            // f32 [512]
constexpr size_t OFF_INV  = OFF_BV + 4096;            // f32 [32][256]
constexpr size_t OFF_PART = OFF_INV + 32768;          // f32 [32][8][256]
constexpr size_t OFF_LOG  = 2u << 20;                 // u16 [32768][256] (16 MiB)
constexpr size_t OFF_XB   = OFF_LOG + (16u << 20);    // u16 [32768][512] (32 MiB)

__device__ __forceinline__ float bf2f(u16 v) {
  union { u32 u; float f; } c; c.u = ((u32)v) << 16; return c.f;
}
__device__ __forceinline__ u16 f2bf(float f) {
  union { float f; u32 u; } c; c.f = f;
  u32 u = c.u;
  u += 0x7fffu + ((u >> 16) & 1u);
  return (u16)(u >> 16);
}

__device__ __forceinline__ void mfma_bf16(f32x4& acc, s16x8 a, s16x8 b) {
  asm volatile("v_mfma_f32_16x16x32_bf16 %0, %1, %2, %0"
               : "+v"(acc) : "v"(a), "v"(b));
}

// ---------------------------------------------------------------------------
// mode detector: sample even ushort indices of x. If the buffer is bf16, every
// sample is a sane N(0,1)-scale bf16 (exp field near 127). If it is fp32, even
// ushorts are mantissa bits -> uniform exponent -> ~22% sane. flag=1 => bf16.
__global__ void detect_mode(const void* __restrict__ x, int* __restrict__ flag) {
  const int t = threadIdx.x;  // 64 threads, one wave
  const u16 v = ((const u16*)x)[t * 262144];
  const int ex = (v >> 7) & 0xFF;
  const bool sane = (ex == 0) || (ex >= 88 && ex <= 143);
  unsigned long long m = __ballot(sane);
  if (t == 0) flag[0] = (__popcll(m) >= 40) ? 1 : 0;
}

// x -> bf16 canonical buffer (copy or downconvert), 8 elements/thread
__global__ void conv_x(const void* __restrict__ x, const int* __restrict__ flag,
                       u16* __restrict__ xb) {
  const int gid = blockIdx.x * 256 + threadIdx.x;  // 0 .. 2097151
  if (flag[0]) {
    ((uint4*)xb)[gid] = ((const uint4*)x)[gid];
  } else {
    const float4* xf = (const float4*)x;
    float4 f0 = xf[gid * 2], f1 = xf[gid * 2 + 1];
    u32 p0 = (u32)f2bf(f0.x) | ((u32)f2bf(f0.y) << 16);
    u32 p1 = (u32)f2bf(f0.z) | ((u32)f2bf(f0.w) << 16);
    u32 p2 = (u32)f2bf(f1.x) | ((u32)f2bf(f1.y) << 16);
    u32 p3 = (u32)f2bf(f1.z) | ((u32)f2bf(f1.w) << 16);
    ((uint4*)xb)[gid] = make_uint4(p0, p1, p2, p3);
  }
}

// WkT[hm][e] = sum_d W_in[e, h*128+d] * W_mk[d, m]   (stored transposed, bf16)
__global__ void prep_wkt(const void* __restrict__ W_in, const void* __restrict__ W_mk,
                         const int* __restrict__ flag, u16* __restrict__ wkT) {
  const int gid = blockIdx.x * 256 + threadIdx.x;
  const int hm = gid & 255, e = gid >> 8;
  const int h = hm >> 4, m = hm & 15;
  float acc = 0.f;
  if (flag[0]) {
    const u16* wi = (const u16*)W_in; const u16* wm = (const u16*)W_mk;
    for (int d = 0; d < 128; d++)
      acc += bf2f(wi[e * 2048 + h * 128 + d]) * bf2f(wm[d * 16 + m]);
  } else {
    const float* wi = (const float*)W_in; const float* wm = (const float*)W_mk;
    for (int d = 0; d < 128; d++)
      acc += wi[e * 2048 + h * 128 + d] * wm[d * 16 + m];
  }
  wkT[hm * 512 + e] = f2bf(acc);
}

// WvT[e][hm] = sum_d W_mv[m,d] * W_out[h*128+d, e]   (stored transposed, bf16)
__global__ void prep_wvt(const void* __restrict__ W_mv, const void* __restrict__ W_out,
                         const int* __restrict__ flag, u16* __restrict__ wvT) {
  const int gid = blockIdx.x * 256 + threadIdx.x;
  const int hm = gid & 255, e = gid >> 8;
  const int h = hm >> 4, m = hm & 15;
  float acc = 0.f;
  if (flag[0]) {
    const u16* mv = (const u16*)W_mv; const u16* wo = (const u16*)W_out;
    for (int d = 0; d < 128; d++)
      acc += bf2f(mv[m * 128 + d]) * bf2f(wo[(h * 128 + d) * 512 + e]);
  } else {
    const float* mv = (const float*)W_mv; const float* wo = (const float*)W_out;
    for (int d = 0; d < 128; d++)
      acc += mv[m * 128 + d] * wo[(h * 128 + d) * 512 + e];
  }
  wvT[e * 256 + hm] = f2bf(acc);
}

// bk[hm] = b_mk[m] + sum_d b_in[h*128+d]*W_mk[d,m]
// bv[e]  = b_out[e] + sum_c b_mv[c&127]*W_out[c,e]
__global__ void prep_bias(const void* __restrict__ b_in, const void* __restrict__ W_mk,
                          const void* __restrict__ b_mk, const void* __restrict__ b_mv,
                          const void* __restrict__ W_out, const void* __restrict__ b_out,
                          const int* __restrict__ flag,
                          float* __restrict__ bk, float* __restrict__ bv) {
  const int t = threadIdx.x;
  const bool m16 = flag[0] != 0;
  if (blockIdx.x == 0) {
    const int h = t >> 4, m = t & 15;
    float acc;
    if (m16) {
      acc = bf2f(((const u16*)b_mk)[m]);
      const u16* bi = (const u16*)b_in; const u16* wm = (const u16*)W_mk;
      for (int d = 0; d < 128; d++)
        acc += bf2f(bi[h * 128 + d]) * bf2f(wm[d * 16 + m]);
    } else {
      acc = ((const float*)b_mk)[m];
      const float* bi = (const float*)b_in; const float* wm = (const float*)W_mk;
      for (int d = 0; d < 128; d++)
        acc += bi[h * 128 + d] * wm[d * 16 + m];
    }
    bk[t] = acc;
  } else {
    const int e = (blockIdx.x - 1) * 256 + t;
    float acc;
    if (m16) {
      acc = bf2f(((const u16*)b_out)[e]);
      const u16* bm = (const u16*)b_mv; const u16* wo = (const u16*)W_out;
      for (int c = 0; c < 2048; c++)
        acc += bf2f(bm[c & 127]) * bf2f(wo[c * 512 + e]);
    } else {
      acc = ((const float*)b_out)[e];
      const float* bm = (const float*)b_mv; const float* wo = (const float*)W_out;
      for (int c = 0; c < 2048; c++)
        acc += bm[c & 127] * wo[c * 512 + e];
    }
    bv[e] = acc;
  }
}

// ---------------------------------------------------------------------------
// GEMM A: logits[32768,256] = xb[32768,512] @ Wk (via WkT) + bk, stored bf16.
// 128x128 tile, BK=32, 4 waves (2x2), 16x16x32 MFMA.
// LDS cells: [kg][row] of 8 bf16 (16 B) -> conflict-free ds_read_b128.
__global__ __launch_bounds__(256) void gemm_a(const u16* __restrict__ xb,
                                              const u16* __restrict__ wkT,
                                              const float* __restrict__ bk,
                                              u16* __restrict__ logits) {
  __shared__ u16 As[4096];  // 4 kg * 128 rows * 8
  __shared__ u16 Bs[4096];
  const int t = threadIdx.x;
  const int l = t & 63, w = t >> 6;
  const int wr = w >> 1, wc = w & 1;
  const int lrow = l & 15, lkg = l >> 4;
  const int gRow0 = blockIdx.x << 7;
  const int gCol0 = blockIdx.y << 7;
  const int srow = t & 127, skg = t >> 7;

  f32x4 acc[4][4];
#pragma unroll
  for (int i = 0; i < 4; i++)
#pragma unroll
    for (int n = 0; n < 4; n++) acc[i][n] = f32x4{0.f, 0.f, 0.f, 0.f};

  const u16* aSrc = xb + (size_t)(gRow0 + srow) * 512;
  const u16* bSrc = wkT + (size_t)(gCol0 + srow) * 512;

  for (int k0 = 0; k0 < 512; k0 += 32) {
    uint4 a0 = *(const uint4*)(aSrc + k0 + skg * 8);
    uint4 a1 = *(const uint4*)(aSrc + k0 + (skg + 2) * 8);
    uint4 b0 = *(const uint4*)(bSrc + k0 + skg * 8);
    uint4 b1 = *(const uint4*)(bSrc + k0 + (skg + 2) * 8);
    __syncthreads();  // previous iteration's LDS reads complete
    *(uint4*)&As[(skg * 128 + srow) * 8] = a0;
    *(uint4*)&As[((skg + 2) * 128 + srow) * 8] = a1;
    *(uint4*)&Bs[(skg * 128 + srow) * 8] = b0;
    *(uint4*)&Bs[((skg + 2) * 128 + srow) * 8] = b1;
    __syncthreads();
    s16x8 af[4], bfr[4];
#pragma unroll
    for (int i = 0; i < 4; i++)
      af[i] = *(const s16x8*)&As[(lkg * 128 + wr * 64 + i * 16 + lrow) * 8];
#pragma unroll
    for (int n = 0; n < 4; n++)
      bfr[n] = *(const s16x8*)&Bs[(lkg * 128 + wc * 64 + n * 16 + lrow) * 8];
#pragma unroll
    for (int i = 0; i < 4; i++)
#pragma unroll
      for (int n = 0; n < 4; n++) mfma_bf16(acc[i][n], af[i], bfr[n]);
  }
  asm volatile("s_nop 7\n\ts_nop 7");
  const int crow = (l >> 4) * 4;
#pragma unroll
  for (int n = 0; n < 4; n++) {
    const int col = gCol0 + wc * 64 + n * 16 + (l & 15);
    const float bias = bk[col];
#pragma unroll
    for (int i = 0; i < 4; i++) {
      const int row = gRow0 + wr * 64 + i * 16 + crow;
#pragma unroll
      for (int j = 0; j < 4; j++)
        logits[(size_t)(row + j) * 256 + col] = f2bf(acc[i][n][j] + bias);
    }
  }
}

// per-(b,hm) partial sum of exp over 128-row chunk (no max needed: |logit|<~3)
__global__ __launch_bounds__(256) void colsum_part(const u16* __restrict__ logits,
                                                   float* __restrict__ part) {
  const int b = blockIdx.x, ch = blockIdx.y, hm = threadIdx.x;
  const u16* p = logits + ((size_t)(b * 1024 + ch * 128) * 256) + hm;
  float s = 0.f;
#pragma unroll 4
  for (int n = 0; n < 128; n++) s += __expf(bf2f(p[(size_t)n * 256]));
  part[(b * 8 + ch) * 256 + hm] = s;
}

__global__ void colsum_fin(const float* __restrict__ part, float* __restrict__ inv) {
  const int b = blockIdx.x, hm = threadIdx.x;
  float s = 0.f;
#pragma unroll
  for (int c = 0; c < 8; c++) s += part[(b * 8 + c) * 256 + hm];
  inv[b * 256 + hm] = 1.0f / s;
}

// ---------------------------------------------------------------------------
// GEMM B: out[32768,512] = P[32768,256] @ Wv (via WvT) + bv (fp32 out), P
// computed on the fly: p = exp(l)*inv_colsum, L1-normalized per head (16 m's).
// P tile staged bf16 in LDS ([kg][row] cells, XOR-swizzled by kg&7).
__global__ __launch_bounds__(256) void gemm_b(const u16* __restrict__ logits,
                                              const float* __restrict__ inv,
                                              const u16* __restrict__ wvT,
                                              const float* __restrict__ bvv,
                                              float* __restrict__ out) {
  __shared__ u16 Ps[32768];  // 32 kg * 128 rows * 8 = 64 KiB
  __shared__ u16 Bs[4096];   // 8 KiB
  const int t = threadIdx.x;
  const int gRow0 = blockIdx.x << 7;
  const int gCol0 = blockIdx.y << 7;
  const int bIdx = gRow0 >> 10;  // single batch per block

  // phase 1: compute P[128][256] into Ps
  {
    const int h = t & 15;
    const int rl = t >> 4;
    const int kg0 = h * 2;
    float iv[16];
#pragma unroll
    for (int p = 0; p < 16; p++) iv[p] = inv[bIdx * 256 + h * 16 + p];
#pragma unroll
    for (int pass = 0; pass < 8; pass++) {
      const int r = pass * 16 + rl;
      const u16* src = logits + (size_t)(gRow0 + r) * 256 + h * 16;
      uint4 q0 = *(const uint4*)(src);
      uint4 q1 = *(const uint4*)(src + 8);
      const u32 qq[8] = {q0.x, q0.y, q0.z, q0.w, q1.x, q1.y, q1.z, q1.w};
      float e[16];
#pragma unroll
      for (int p = 0; p < 8; p++) {
        e[p * 2]     = __expf(bf2f((u16)(qq[p] & 0xffffu))) * iv[p * 2];
        e[p * 2 + 1] = __expf(bf2f((u16)(qq[p] >> 16)))     * iv[p * 2 + 1];
      }
      float s = 0.f;
#pragma unroll
      for (int p = 0; p < 16; p++) s += e[p];
      const float rs = 1.0f / (s + 1e-9f);
      u32 pk[8];
#pragma unroll
      for (int p = 0; p < 8; p++)
        pk[p] = (u32)f2bf(e[p * 2] * rs) | ((u32)f2bf(e[p * 2 + 1] * rs) << 16);
      *(uint4*)&Ps[(((kg0) * 128 + r) ^ (kg0 & 7)) * 8] =
          make_uint4(pk[0], pk[1], pk[2], pk[3]);
      *(uint4*)&Ps[(((kg0 + 1) * 128 + r) ^ ((kg0 + 1) & 7)) * 8] =
          make_uint4(pk[4], pk[5], pk[6], pk[7]);
    }
  }

  const int l = t & 63, w = t >> 6;
  const int wr = w >> 1, wc = w & 1;
  const int lrow = l & 15, lkg = l >> 4;
  const int srow = t & 127, skg = t >> 7;
  f32x4 acc[4][4];
#pragma unroll
  for (int i = 0; i < 4; i++)
#pragma unroll
    for (int n = 0; n < 4; n++) acc[i][n] = f32x4{0.f, 0.f, 0.f, 0.f};

  const u16* bSrc = wvT + (size_t)(gCol0 + srow) * 256;
  for (int k0 = 0; k0 < 256; k0 += 32) {
    uint4 b0 = *(const uint4*)(bSrc + k0 + skg * 8);
    uint4 b1 = *(const uint4*)(bSrc + k0 + (skg + 2) * 8);
    __syncthreads();  // iter0: also fences phase-1 Ps writes
    *(uint4*)&Bs[(skg * 128 + srow) * 8] = b0;
    *(uint4*)&Bs[((skg + 2) * 128 + srow) * 8] = b1;
    __syncthreads();
    s16x8 af[4], bfr[4];
    const int kgg = (k0 >> 3) + lkg;
#pragma unroll
    for (int i = 0; i < 4; i++)
      af[i] = *(const s16x8*)&Ps[((kgg * 128 + wr * 64 + i * 16 + lrow) ^ (kgg & 7)) * 8];
#pragma unroll
    for (int n = 0; n < 4; n++)
      bfr[n] = *(const s16x8*)&Bs[(lkg * 128 + wc * 64 + n * 16 + lrow) * 8];
#pragma unroll
    for (int i = 0; i < 4; i++)
#pragma unroll
      for (int n = 0; n < 4; n++) mfma_bf16(acc[i][n], af[i], bfr[n]);
  }
  asm volatile("s_nop 7\n\ts_nop 7");
  const int crow = (l >> 4) * 4;
#pragma unroll
  for (int n = 0; n < 4; n++) {
    const int col = gCol0 + wc * 64 + n * 16 + (l & 15);
    const float bias = bvv[col];
#pragma unroll
    for (int i = 0; i < 4; i++) {
      const int row = gRow0 + wr * 64 + i * 16 + crow;
#pragma unroll
      for (int j = 0; j < 4; j++)
        out[(size_t)(row + j) * 512 + col] = acc[i][n][j] + bias;
    }
  }
}

// ---------------------------------------------------------------------------
extern "C" void kernel_launch(void* const* d_in, const int* in_sizes, int n_in,
                              void* d_out, int out_size, void* d_ws, size_t ws_size,
                              hipStream_t stream) {
  (void)in_sizes; (void)n_in; (void)out_size; (void)ws_size;
  const void* x     = d_in[0];
  const void* W_in  = d_in[1];
  const void* b_in  = d_in[2];
  const void* W_mk  = d_in[3];
  const void* b_mk  = d_in[4];
  const void* W_mv  = d_in[5];
  const void* b_mv  = d_in[6];
  const void* W_out = d_in[7];
  const void* b_out = d_in[8];

  char* ws = (char*)d_ws;
  int*   flag = (int*)(ws + OFF_FLAG);
  u16*   wkT  = (u16*)(ws + OFF_WKT);
  u16*   wvT  = (u16*)(ws + OFF_WVT);
  float* bk   = (float*)(ws + OFF_BK);
  float* bv   = (float*)(ws + OFF_BV);
  float* inv  = (float*)(ws + OFF_INV);
  float* part = (float*)(ws + OFF_PART);
  u16*   lg   = (u16*)(ws + OFF_LOG);
  u16*   xb   = (u16*)(ws + OFF_XB);
  float* outp = (float*)d_out;

  detect_mode<<<1, 64, 0, stream>>>(x, flag);
  conv_x<<<8192, 256, 0, stream>>>(x, flag, xb);
  prep_wkt<<<512, 256, 0, stream>>>(W_in, W_mk, flag, wkT);
  prep_wvt<<<512, 256, 0, stream>>>(W_mv, W_out, flag, wvT);
  prep_bias<<<3, 256, 0, stream>>>(b_in, W_mk, b_mk, b_mv, W_out, b_out, flag, bk, bv);
  gemm_a<<<dim3(256, 2), 256, 0, stream>>>(xb, wkT, bk, lg);
  colsum_part<<<dim3(32, 8), 256, 0, stream>>>(lg, part);
  colsum_fin<<<32, 256, 0, stream>>>(part, inv);
  gemm_b<<<dim3(256, 4), 256, 0, stream>>>(lg, inv, wvT, bv, outp);
}

// Round 3
// 109.000 us; speedup vs baseline: 1.5288x; 1.5288x over previous
//
#include <hip/hip_runtime.h>
#include <cstdint>
#include <cstddef>

// ---------------------------------------------------------------------------
// MultiHeadExternalAttention, algebraically collapsed:
//   logits = x @ Wk   (Wk[e,hm] = sum_d W_in[e,h*128+d]*W_mk[d,m]) + bk
//   attn   = softmax_n(logits); attn /= (sum_m attn + 1e-9)
//   out    = attn @ Wv (Wv[hm,e] = sum_d W_mv[m,d]*W_out[h*128+d,e]) + bv
// B=32 N=1024 E=512 H=16 M=16 HM=256 ROWS=32768
// Inputs fp32, output fp32 (confirmed round 2). Internals bf16 via MFMA.
// ---------------------------------------------------------------------------

typedef unsigned short u16;
typedef unsigned int u32;
typedef short s16x8 __attribute__((ext_vector_type(8)));
typedef float f32x4 __attribute__((ext_vector_type(4)));

// workspace layout (bytes)
constexpr size_t OFF_BVP  = 0;                        // f32 [32][512] (64 KiB)
constexpr size_t OFF_WKT  = 1u << 20;                 // u16 [256][512]  (256 KiB)
constexpr size_t OFF_WVT  = OFF_WKT + (1u << 18);     // u16 [512][256]  (256 KiB)
constexpr size_t OFF_BK   = OFF_WVT + (1u << 18);     // f32 [256]
constexpr size_t OFF_BV   = OFF_BK + 4096;            // f32 [512]
constexpr size_t OFF_INV  = OFF_BV + 4096;            // f32 [32][256]
constexpr size_t OFF_PART = OFF_INV + 32768;          // f32 [32][8][256]
constexpr size_t OFF_LOG  = 2u << 20;                 // u16 [32768][256] (16 MiB)

__device__ __forceinline__ float bf2f(u16 v) {
  union { u32 u; float f; } c; c.u = ((u32)v) << 16; return c.f;
}
__device__ __forceinline__ u16 f2bf(float f) {
  union { float f; u32 u; } c; c.f = f;
  u32 u = c.u;
  u += 0x7fffu + ((u >> 16) & 1u);
  return (u16)(u >> 16);
}
__device__ __forceinline__ uint4 pack_bf8(float4 lo, float4 hi) {
  return make_uint4((u32)f2bf(lo.x) | ((u32)f2bf(lo.y) << 16),
                    (u32)f2bf(lo.z) | ((u32)f2bf(lo.w) << 16),
                    (u32)f2bf(hi.x) | ((u32)f2bf(hi.y) << 16),
                    (u32)f2bf(hi.z) | ((u32)f2bf(hi.w) << 16));
}

__device__ __forceinline__ void mfma_bf16(f32x4& acc, s16x8 a, s16x8 b) {
  asm volatile("v_mfma_f32_16x16x32_bf16 %0, %1, %2, %0"
               : "+v"(acc) : "v"(a), "v"(b));
}

// ---------------------------------------------------------------------------
// WkT[hm][e] = sum_d W_in[e, h*128+d] * W_mk[d, m]   (stored transposed, bf16)
__global__ void prep_wkt(const float* __restrict__ wi, const float* __restrict__ wm,
                         u16* __restrict__ wkT) {
  const int gid = blockIdx.x * 256 + threadIdx.x;
  const int hm = gid & 255, e = gid >> 8;
  const int h = hm >> 4, m = hm & 15;
  float acc = 0.f;
  for (int d = 0; d < 128; d++)
    acc += wi[e * 2048 + h * 128 + d] * wm[d * 16 + m];
  wkT[hm * 512 + e] = f2bf(acc);
}

// WvT[e][hm] = sum_d W_mv[m,d] * W_out[h*128+d, e]   (stored transposed, bf16)
__global__ void prep_wvt(const float* __restrict__ mv, const float* __restrict__ wo,
                         u16* __restrict__ wvT) {
  const int gid = blockIdx.x * 256 + threadIdx.x;
  const int hm = gid & 255, e = gid >> 8;
  const int h = hm >> 4, m = hm & 15;
  float acc = 0.f;
  for (int d = 0; d < 128; d++)
    acc += mv[m * 128 + d] * wo[(h * 128 + d) * 512 + e];
  wvT[e * 256 + hm] = f2bf(acc);
}

// bk[hm] = b_mk[m] + sum_d b_in[h*128+d]*W_mk[d,m]   (1 block, cached reads)
__global__ void prep_bk(const float* __restrict__ b_in, const float* __restrict__ wm,
                        const float* __restrict__ b_mk, float* __restrict__ bk) {
  const int t = threadIdx.x;
  const int h = t >> 4, m = t & 15;
  float acc = b_mk[m];
  for (int d = 0; d < 128; d++) acc += b_in[h * 128 + d] * wm[d * 16 + m];
  bk[t] = acc;
}

// bv partial: block k reduces 64 coalesced rows of W_out weighted by b_mv
__global__ void bv_part(const float* __restrict__ wo, const float* __restrict__ b_mv,
                        float* __restrict__ bvp) {
  const int k = blockIdx.x;   // 32
  const int t = threadIdx.x;  // 256
  float a0 = 0.f, a1 = 0.f;
  const int c0 = k * 64;
#pragma unroll 8
  for (int c = c0; c < c0 + 64; c++) {
    const float w = b_mv[c & 127];
    a0 += w * wo[(size_t)c * 512 + t];
    a1 += w * wo[(size_t)c * 512 + 256 + t];
  }
  bvp[k * 512 + t] = a0;
  bvp[k * 512 + 256 + t] = a1;
}

// bv[e] = b_out[e] + sum_k bvp[k][e]
__global__ void bv_fin(const float* __restrict__ bvp, const float* __restrict__ b_out,
                       float* __restrict__ bv) {
  const int e = blockIdx.x * 256 + threadIdx.x;  // 512
  float s = b_out[e];
#pragma unroll
  for (int k = 0; k < 32; k++) s += bvp[k * 512 + e];
  bv[e] = s;
}

// ---------------------------------------------------------------------------
// GEMM A: logits[32768,256] = x[32768,512](fp32, cvt in-reg) @ Wk + bk, bf16.
// 128x128 tile, BK=32, 4 waves (2x2), 16x16x32 MFMA.
// grid (2,256): x = col-block so both col-blocks of a row-panel are
// dispatch-adjacent (L2/L3 reuse of the fp32 A-panel second read).
// LDS cells: [kg][row] of 8 bf16 (16 B) -> conflict-free ds_read_b128.
__global__ __launch_bounds__(256) void gemm_a(const float* __restrict__ x,
                                              const u16* __restrict__ wkT,
                                              const float* __restrict__ bk,
                                              u16* __restrict__ logits) {
  __shared__ u16 As[4096];  // 4 kg * 128 rows * 8
  __shared__ u16 Bs[4096];
  const int t = threadIdx.x;
  const int l = t & 63, w = t >> 6;
  const int wr = w >> 1, wc = w & 1;
  const int lrow = l & 15, lkg = l >> 4;
  const int gCol0 = blockIdx.x << 7;
  const int gRow0 = blockIdx.y << 7;
  const int srow = t & 127, skg = t >> 7;

  f32x4 acc[4][4];
#pragma unroll
  for (int i = 0; i < 4; i++)
#pragma unroll
    for (int n = 0; n < 4; n++) acc[i][n] = f32x4{0.f, 0.f, 0.f, 0.f};

  const float* aSrc = x + (size_t)(gRow0 + srow) * 512;
  const u16* bSrc = wkT + (size_t)(gCol0 + srow) * 512;

  for (int k0 = 0; k0 < 512; k0 += 32) {
    float4 fa0 = *(const float4*)(aSrc + k0 + skg * 8);
    float4 fa1 = *(const float4*)(aSrc + k0 + skg * 8 + 4);
    float4 fa2 = *(const float4*)(aSrc + k0 + (skg + 2) * 8);
    float4 fa3 = *(const float4*)(aSrc + k0 + (skg + 2) * 8 + 4);
    uint4 b0 = *(const uint4*)(bSrc + k0 + skg * 8);
    uint4 b1 = *(const uint4*)(bSrc + k0 + (skg + 2) * 8);
    uint4 a0 = pack_bf8(fa0, fa1);
    uint4 a1 = pack_bf8(fa2, fa3);
    __syncthreads();  // previous iteration's LDS reads complete
    *(uint4*)&As[(skg * 128 + srow) * 8] = a0;
    *(uint4*)&As[((skg + 2) * 128 + srow) * 8] = a1;
    *(uint4*)&Bs[(skg * 128 + srow) * 8] = b0;
    *(uint4*)&Bs[((skg + 2) * 128 + srow) * 8] = b1;
    __syncthreads();
    s16x8 af[4], bfr[4];
#pragma unroll
    for (int i = 0; i < 4; i++)
      af[i] = *(const s16x8*)&As[(lkg * 128 + wr * 64 + i * 16 + lrow) * 8];
#pragma unroll
    for (int n = 0; n < 4; n++)
      bfr[n] = *(const s16x8*)&Bs[(lkg * 128 + wc * 64 + n * 16 + lrow) * 8];
#pragma unroll
    for (int i = 0; i < 4; i++)
#pragma unroll
      for (int n = 0; n < 4; n++) mfma_bf16(acc[i][n], af[i], bfr[n]);
  }
  asm volatile("s_nop 7\n\ts_nop 7");
  const int crow = (l >> 4) * 4;
#pragma unroll
  for (int n = 0; n < 4; n++) {
    const int col = gCol0 + wc * 64 + n * 16 + (l & 15);
    const float bias = bk[col];
#pragma unroll
    for (int i = 0; i < 4; i++) {
      const int row = gRow0 + wr * 64 + i * 16 + crow;
#pragma unroll
      for (int j = 0; j < 4; j++)
        logits[(size_t)(row + j) * 256 + col] = f2bf(acc[i][n][j] + bias);
    }
  }
}

// per-(b,hm) partial sum of exp over 128-row chunk (no max needed: |logit|<~3)
__global__ __launch_bounds__(256) void colsum_part(const u16* __restrict__ logits,
                                                   float* __restrict__ part) {
  const int b = blockIdx.x, ch = blockIdx.y, hm = threadIdx.x;
  const u16* p = logits + ((size_t)(b * 1024 + ch * 128) * 256) + hm;
  float s = 0.f;
#pragma unroll 4
  for (int n = 0; n < 128; n++) s += __expf(bf2f(p[(size_t)n * 256]));
  part[(b * 8 + ch) * 256 + hm] = s;
}

__global__ void colsum_fin(const float* __restrict__ part, float* __restrict__ inv) {
  const int b = blockIdx.x, hm = threadIdx.x;
  float s = 0.f;
#pragma unroll
  for (int c = 0; c < 8; c++) s += part[(b * 8 + c) * 256 + hm];
  inv[b * 256 + hm] = 1.0f / s;
}

// ---------------------------------------------------------------------------
// GEMM B: out[32768,512] = P[32768,256] @ Wv (via WvT) + bv (fp32 out), P
// computed on the fly: p = exp(l)*inv_colsum, L1-normalized per head (16 m's).
// P tile staged bf16 in LDS ([kg][row] cells, XOR-swizzled by kg&7).
__global__ __launch_bounds__(256) void gemm_b(const u16* __restrict__ logits,
                                              const float* __restrict__ inv,
                                              const u16* __restrict__ wvT,
                                              const float* __restrict__ bvv,
                                              float* __restrict__ out) {
  __shared__ u16 Ps[32768];  // 32 kg * 128 rows * 8 = 64 KiB
  __shared__ u16 Bs[4096];   // 8 KiB
  const int t = threadIdx.x;
  const int gRow0 = blockIdx.x << 7;
  const int gCol0 = blockIdx.y << 7;
  const int bIdx = gRow0 >> 10;  // single batch per block

  // phase 1: compute P[128][256] into Ps
  {
    const int h = t & 15;
    const int rl = t >> 4;
    const int kg0 = h * 2;
    float iv[16];
#pragma unroll
    for (int p = 0; p < 16; p++) iv[p] = inv[bIdx * 256 + h * 16 + p];
#pragma unroll
    for (int pass = 0; pass < 8; pass++) {
      const int r = pass * 16 + rl;
      const u16* src = logits + (size_t)(gRow0 + r) * 256 + h * 16;
      uint4 q0 = *(const uint4*)(src);
      uint4 q1 = *(const uint4*)(src + 8);
      const u32 qq[8] = {q0.x, q0.y, q0.z, q0.w, q1.x, q1.y, q1.z, q1.w};
      float e[16];
#pragma unroll
      for (int p = 0; p < 8; p++) {
        e[p * 2]     = __expf(bf2f((u16)(qq[p] & 0xffffu))) * iv[p * 2];
        e[p * 2 + 1] = __expf(bf2f((u16)(qq[p] >> 16)))     * iv[p * 2 + 1];
      }
      float s = 0.f;
#pragma unroll
      for (int p = 0; p < 16; p++) s += e[p];
      const float rs = 1.0f / (s + 1e-9f);
      u32 pk[8];
#pragma unroll
      for (int p = 0; p < 8; p++)
        pk[p] = (u32)f2bf(e[p * 2] * rs) | ((u32)f2bf(e[p * 2 + 1] * rs) << 16);
      *(uint4*)&Ps[(((kg0) * 128 + r) ^ (kg0 & 7)) * 8] =
          make_uint4(pk[0], pk[1], pk[2], pk[3]);
      *(uint4*)&Ps[(((kg0 + 1) * 128 + r) ^ ((kg0 + 1) & 7)) * 8] =
          make_uint4(pk[4], pk[5], pk[6], pk[7]);
    }
  }

  const int l = t & 63, w = t >> 6;
  const int wr = w >> 1, wc = w & 1;
  const int lrow = l & 15, lkg = l >> 4;
  const int srow = t & 127, skg = t >> 7;
  f32x4 acc[4][4];
#pragma unroll
  for (int i = 0; i < 4; i++)
#pragma unroll
    for (int n = 0; n < 4; n++) acc[i][n] = f32x4{0.f, 0.f, 0.f, 0.f};

  const u16* bSrc = wvT + (size_t)(gCol0 + srow) * 256;
  for (int k0 = 0; k0 < 256; k0 += 32) {
    uint4 b0 = *(const uint4*)(bSrc + k0 + skg * 8);
    uint4 b1 = *(const uint4*)(bSrc + k0 + (skg + 2) * 8);
    __syncthreads();  // iter0: also fences phase-1 Ps writes
    *(uint4*)&Bs[(skg * 128 + srow) * 8] = b0;
    *(uint4*)&Bs[((skg + 2) * 128 + srow) * 8] = b1;
    __syncthreads();
    s16x8 af[4], bfr[4];
    const int kgg = (k0 >> 3) + lkg;
#pragma unroll
    for (int i = 0; i < 4; i++)
      af[i] = *(const s16x8*)&Ps[((kgg * 128 + wr * 64 + i * 16 + lrow) ^ (kgg & 7)) * 8];
#pragma unroll
    for (int n = 0; n < 4; n++)
      bfr[n] = *(const s16x8*)&Bs[(lkg * 128 + wc * 64 + n * 16 + lrow) * 8];
#pragma unroll
    for (int i = 0; i < 4; i++)
#pragma unroll
      for (int n = 0; n < 4; n++) mfma_bf16(acc[i][n], af[i], bfr[n]);
  }
  asm volatile("s_nop 7\n\ts_nop 7");
  const int crow = (l >> 4) * 4;
#pragma unroll
  for (int n = 0; n < 4; n++) {
    const int col = gCol0 + wc * 64 + n * 16 + (l & 15);
    const float bias = bvv[col];
#pragma unroll
    for (int i = 0; i < 4; i++) {
      const int row = gRow0 + wr * 64 + i * 16 + crow;
#pragma unroll
      for (int j = 0; j < 4; j++)
        out[(size_t)(row + j) * 512 + col] = acc[i][n][j] + bias;
    }
  }
}

// ---------------------------------------------------------------------------
extern "C" void kernel_launch(void* const* d_in, const int* in_sizes, int n_in,
                              void* d_out, int out_size, void* d_ws, size_t ws_size,
                              hipStream_t stream) {
  (void)in_sizes; (void)n_in; (void)out_size; (void)ws_size;
  const float* x     = (const float*)d_in[0];
  const float* W_in  = (const float*)d_in[1];
  const float* b_in  = (const float*)d_in[2];
  const float* W_mk  = (const float*)d_in[3];
  const float* b_mk  = (const float*)d_in[4];
  const float* W_mv  = (const float*)d_in[5];
  const float* b_mv  = (const float*)d_in[6];
  const float* W_out = (const float*)d_in[7];
  const float* b_out = (const float*)d_in[8];

  char* ws = (char*)d_ws;
  float* bvp  = (float*)(ws + OFF_BVP);
  u16*   wkT  = (u16*)(ws + OFF_WKT);
  u16*   wvT  = (u16*)(ws + OFF_WVT);
  float* bk   = (float*)(ws + OFF_BK);
  float* bv   = (float*)(ws + OFF_BV);
  float* inv  = (float*)(ws + OFF_INV);
  float* part = (float*)(ws + OFF_PART);
  u16*   lg   = (u16*)(ws + OFF_LOG);
  float* outp = (float*)d_out;

  prep_wkt<<<512, 256, 0, stream>>>(W_in, W_mk, wkT);
  prep_wvt<<<512, 256, 0, stream>>>(W_mv, W_out, wvT);
  prep_bk<<<1, 256, 0, stream>>>(b_in, W_mk, b_mk, bk);
  bv_part<<<32, 256, 0, stream>>>(W_out, b_mv, bvp);
  bv_fin<<<2, 256, 0, stream>>>(bvp, b_out, bv);
  gemm_a<<<dim3(2, 256), 256, 0, stream>>>(x, wkT, bk, lg);
  colsum_part<<<dim3(32, 8), 256, 0, stream>>>(lg, part);
  colsum_fin<<<32, 256, 0, stream>>>(part, inv);
  gemm_b<<<dim3(256, 4), 256, 0, stream>>>(lg, inv, wvT, bv, outp);
}